// Round 2
// baseline (693.156 us; speedup 1.0000x reference)
//
#include <hip/hip_runtime.h>
#include <math.h>

#define Cc 16
#define Bb 64
#define Rr 1152
#define Ii 64
#define Oo 64
#define RT 8

static __device__ __forceinline__ float4 ld4(const float* p){ return *reinterpret_cast<const float4*>(p); }
static __device__ __forceinline__ void st4(float* p, float4 v){ *reinterpret_cast<float4*>(p) = v; }

// ---- small scratch as device globals (no dependence on ws_size) ----
__device__ float gProbs0[Cc*Rr];                 //  72 KB
__device__ float gS[Cc*Bb*Oo];                   // 256 KB
__device__ float gOut[Cc*Bb*Oo];                 // 256 KB
__device__ float gL1[(size_t)Cc*Bb*Rr];          // 4.7 MB
__device__ float gLp[(size_t)Cc*Bb*Rr];          // 4.7 MB

__global__ void kz_zeroS(){
  const int i = blockIdx.x*256 + threadIdx.x;
  if (i < Cc*Bb*Oo) gS[i] = 0.f;
}

// ---- softmax over a row of length Rr, block=256 ----
static __device__ void softmax_row(const float* __restrict__ L, float* __restrict__ out,
                                   float* __restrict__ sred /*>=8 floats*/){
  const int tid = threadIdx.x;
  float m = -3.4e38f;
  for (int r = tid; r < Rr; r += 256) m = fmaxf(m, L[r]);
  #pragma unroll
  for (int off = 1; off < 64; off <<= 1) m = fmaxf(m, __shfl_xor(m, off));
  if ((tid & 63) == 0) sred[tid >> 6] = m;
  __syncthreads();
  m = fmaxf(fmaxf(sred[0], sred[1]), fmaxf(sred[2], sred[3]));
  float s = 0.f;
  for (int r = tid; r < Rr; r += 256) s += __expf(L[r] - m);
  #pragma unroll
  for (int off = 1; off < 64; off <<= 1) s += __shfl_xor(s, off);
  if ((tid & 63) == 0) sred[4 + (tid >> 6)] = s;
  __syncthreads();
  s = sred[4] + sred[5] + sred[6] + sred[7];
  const float inv = 1.0f / s;
  for (int r = tid; r < Rr; r += 256) out[r] = __expf(L[r] - m) * inv;
}

__global__ void k0f(const float* __restrict__ lg){
  __shared__ float sred[8];
  const int c = blockIdx.x;
  softmax_row(lg + c*Rr, gProbs0 + c*Rr, sred);
}

// ---- shared 64x64x64 per-r GEMM: acc[j] = X[tb+j, r, :] @ W[c,r][:, to..to+3] ----
static __device__ __forceinline__ void fma_row(float4& a, const float4 xv,
    const float4 w0, const float4 w1, const float4 w2, const float4 w3){
  a.x = fmaf(xv.x, w0.x, fmaf(xv.y, w1.x, fmaf(xv.z, w2.x, fmaf(xv.w, w3.x, a.x))));
  a.y = fmaf(xv.x, w0.y, fmaf(xv.y, w1.y, fmaf(xv.z, w2.y, fmaf(xv.w, w3.y, a.y))));
  a.z = fmaf(xv.x, w0.z, fmaf(xv.y, w1.z, fmaf(xv.z, w2.z, fmaf(xv.w, w3.z, a.z))));
  a.w = fmaf(xv.x, w0.w, fmaf(xv.y, w1.w, fmaf(xv.z, w2.w, fmaf(xv.w, w3.w, a.w))));
}

static __device__ void stage_gemm(const float* __restrict__ x, const float* __restrict__ w,
                                  int c, int r, int tid, int tb, int to,
                                  float* __restrict__ Xs, float* __restrict__ Ws,
                                  float4* __restrict__ acc){
  const float4* wsrc = reinterpret_cast<const float4*>(w + (size_t)(c*Rr + r) * (Ii*Oo));
  #pragma unroll
  for (int qq = 0; qq < 4; ++qq) {
    const int fi = tid + 256*qq;                 // float4 index 0..1023
    reinterpret_cast<float4*>(Ws)[fi] = wsrc[fi];
    const int b  = fi >> 4;
    const int i4 = (fi & 15) << 2;
    st4(&Xs[b*68 + i4], ld4(x + (size_t)(b*Rr + r)*Ii + i4));
  }
  __syncthreads();
  #pragma unroll
  for (int j = 0; j < 4; ++j) acc[j] = make_float4(0.f,0.f,0.f,0.f);
  #pragma unroll
  for (int i4 = 0; i4 < Ii; i4 += 4) {
    const float4 xv0 = ld4(&Xs[(tb+0)*68 + i4]);
    const float4 xv1 = ld4(&Xs[(tb+1)*68 + i4]);
    const float4 xv2 = ld4(&Xs[(tb+2)*68 + i4]);
    const float4 xv3 = ld4(&Xs[(tb+3)*68 + i4]);
    const float4 wv0 = ld4(&Ws[(i4+0)*64 + to]);
    const float4 wv1 = ld4(&Ws[(i4+1)*64 + to]);
    const float4 wv2 = ld4(&Ws[(i4+2)*64 + to]);
    const float4 wv3 = ld4(&Ws[(i4+3)*64 + to]);
    fma_row(acc[0], xv0, wv0, wv1, wv2, wv3);
    fma_row(acc[1], xv1, wv0, wv1, wv2, wv3);
    fma_row(acc[2], xv2, wv0, wv1, wv2, wv3);
    fma_row(acc[3], xv3, wv0, wv1, wv2, wv3);
  }
}

// ================= FAST PATH (needs ws >= C*B*R*O floats) =================
__launch_bounds__(256)
__global__ void k1_priors(const float* __restrict__ x, const float* __restrict__ w,
                          float* __restrict__ P){
  const int c   = blockIdx.x;
  const int r0  = blockIdx.y * RT;
  const int tid = threadIdx.x;
  const int to  = (tid & 15) * 4;
  const int tb  = (tid >> 4) * 4;
  __shared__ float Xs[64*68];
  __shared__ float Ws[64*64];

  float4 s0a[4];
  #pragma unroll
  for (int j = 0; j < 4; ++j) s0a[j] = make_float4(0.f,0.f,0.f,0.f);

  for (int rr = 0; rr < RT; ++rr) {
    const int r = r0 + rr;
    float4 acc[4];
    stage_gemm(x, w, c, r, tid, tb, to, Xs, Ws, acc);
    const float pr = gProbs0[c*Rr + r];
    #pragma unroll
    for (int j = 0; j < 4; ++j) {
      st4(&P[((size_t)(c*Bb + tb + j)*Rr + r)*Oo + to], acc[j]);
      s0a[j].x = fmaf(pr, acc[j].x, s0a[j].x);
      s0a[j].y = fmaf(pr, acc[j].y, s0a[j].y);
      s0a[j].z = fmaf(pr, acc[j].z, s0a[j].z);
      s0a[j].w = fmaf(pr, acc[j].w, s0a[j].w);
    }
    __syncthreads();
  }
  #pragma unroll
  for (int j = 0; j < 4; ++j) {
    float* dst = &gS[(size_t)(c*Bb + tb + j)*Oo + to];
    atomicAdd(dst + 0, s0a[j].x);
    atomicAdd(dst + 1, s0a[j].y);
    atomicAdd(dst + 2, s0a[j].z);
    atomicAdd(dst + 3, s0a[j].w);
  }
}

__launch_bounds__(256)
__global__ void k3_routing(const float* __restrict__ P, const float* __restrict__ lg0g,
                           float* __restrict__ out){
  const int b = blockIdx.x, c = blockIdx.y;
  const int tid  = threadIdx.x;
  const int wv   = tid >> 6;
  const int lane = tid & 63;
  const int g    = lane >> 4;
  const int q    = lane & 15;
  const int o4   = q * 4;
  const int pid  = wv*4 + g;

  __shared__ float lg0[Rr];
  __shared__ float lgs1[Rr];
  __shared__ float outv[Oo];
  __shared__ float marr[16], larr[16];
  __shared__ float sarr[16*Oo];

  for (int r = tid; r < Rr; r += 256) lg0[r] = lg0g[c*Rr + r];

  if (tid < 64) {
    const float s = gS[(size_t)(c*Bb + b)*Oo + tid];
    float t2 = s*s;
    #pragma unroll
    for (int off = 1; off < 64; off <<= 1) t2 += __shfl_xor(t2, off);
    outv[tid] = s * (t2 / ((1.0f + t2) * sqrtf(t2)));
  }
  __syncthreads();

  const float4* Pcb = reinterpret_cast<const float4*>(P + (size_t)(c*Bb + b)*Rr*Oo);

  #pragma unroll 1
  for (int pass = 1; pass <= 2; ++pass) {
    float m = -3.4e38f, l = 0.f;
    float4 sa = make_float4(0.f,0.f,0.f,0.f);
    const float4 ov = ld4(&outv[o4]);

    for (int step = 0; step < Rr/16; ++step) {
      const int r = step*16 + wv*4 + g;
      const float4 pv = Pcb[r*16 + q];
      float d = pv.x*ov.x + pv.y*ov.y + pv.z*ov.z + pv.w*ov.w;
      d += __shfl_xor(d, 1);
      d += __shfl_xor(d, 2);
      d += __shfl_xor(d, 4);
      d += __shfl_xor(d, 8);
      const float base = (pass == 1) ? lg0[r] : lgs1[r];
      const float lgt  = base + d;
      if (pass == 1 && q == 0) lgs1[r] = lgt;
      const float nm = fmaxf(m, lgt);
      const float wo = __expf(m - nm);
      const float wn = __expf(lgt - nm);
      l = l*wo + wn;
      sa.x = fmaf(pv.x, wn, sa.x*wo);
      sa.y = fmaf(pv.y, wn, sa.y*wo);
      sa.z = fmaf(pv.z, wn, sa.z*wo);
      sa.w = fmaf(pv.w, wn, sa.w*wo);
      m = nm;
    }

    if (q == 0) { marr[pid] = m; larr[pid] = l; }
    st4(&sarr[pid*Oo + o4], sa);
    __syncthreads();

    if (tid < 64) {
      float M = -3.4e38f;
      #pragma unroll
      for (int p = 0; p < 16; ++p) M = fmaxf(M, marr[p]);
      float L = 0.f, sv = 0.f;
      #pragma unroll
      for (int p = 0; p < 16; ++p) {
        const float f = __expf(marr[p] - M);
        L += larr[p] * f;
        sv += sarr[p*Oo + tid] * f;
      }
      const float s = sv / L;
      float t2 = s*s;
      #pragma unroll
      for (int off = 1; off < 64; off <<= 1) t2 += __shfl_xor(t2, off);
      outv[tid] = s * (t2 / ((1.0f + t2) * sqrtf(t2)));
    }
    __syncthreads();
  }

  if (tid < 64) out[(size_t)(c*Bb + b)*Oo + tid] = outv[tid];
}

// ================= FALLBACK PATH (recompute; never touches d_ws) =================
// which: 0 -> weights gProbs0[c,r]; 1 -> gLp[c,b,r]; 2 -> gL1[c,b,r]
__launch_bounds__(256)
__global__ void kf_sum(const float* __restrict__ x, const float* __restrict__ w, int which){
  const int c   = blockIdx.x;
  const int r0  = blockIdx.y * RT;
  const int tid = threadIdx.x;
  const int to  = (tid & 15) * 4;
  const int tb  = (tid >> 4) * 4;
  __shared__ float Xs[64*68];
  __shared__ float Ws[64*64];
  const float* pcbr = (which == 1) ? gLp : gL1;

  float4 sa[4];
  #pragma unroll
  for (int j = 0; j < 4; ++j) sa[j] = make_float4(0.f,0.f,0.f,0.f);

  for (int rr = 0; rr < RT; ++rr) {
    const int r = r0 + rr;
    float4 acc[4];
    stage_gemm(x, w, c, r, tid, tb, to, Xs, Ws, acc);
    #pragma unroll
    for (int j = 0; j < 4; ++j) {
      const float wt = (which == 0) ? gProbs0[c*Rr + r]
                                    : pcbr[(size_t)(c*Bb + tb + j)*Rr + r];
      sa[j].x = fmaf(wt, acc[j].x, sa[j].x);
      sa[j].y = fmaf(wt, acc[j].y, sa[j].y);
      sa[j].z = fmaf(wt, acc[j].z, sa[j].z);
      sa[j].w = fmaf(wt, acc[j].w, sa[j].w);
    }
    __syncthreads();
  }
  #pragma unroll
  for (int j = 0; j < 4; ++j) {
    float* dst = &gS[(size_t)(c*Bb + tb + j)*Oo + to];
    atomicAdd(dst + 0, sa[j].x);
    atomicAdd(dst + 1, sa[j].y);
    atomicAdd(dst + 2, sa[j].z);
    atomicAdd(dst + 3, sa[j].w);
  }
}

// pass 1: L1[c,b,r] = lg[c,r] + prior . gOut ; pass 2: Lp[c,b,r] = L1[c,b,r] + prior . gOut
__launch_bounds__(256)
__global__ void kf_delta(const float* __restrict__ x, const float* __restrict__ w,
                         const float* __restrict__ lg, int pass){
  const int c   = blockIdx.x;
  const int r0  = blockIdx.y * RT;
  const int tid = threadIdx.x;
  const int to  = (tid & 15) * 4;
  const int tb  = (tid >> 4) * 4;
  __shared__ float Xs[64*68];
  __shared__ float Ws[64*64];
  float* dst = (pass == 1) ? gL1 : gLp;

  float4 ov[4];
  #pragma unroll
  for (int j = 0; j < 4; ++j) ov[j] = ld4(&gOut[(size_t)(c*Bb + tb + j)*Oo + to]);

  for (int rr = 0; rr < RT; ++rr) {
    const int r = r0 + rr;
    float4 acc[4];
    stage_gemm(x, w, c, r, tid, tb, to, Xs, Ws, acc);
    float pd[4];
    #pragma unroll
    for (int j = 0; j < 4; ++j) {
      float d = acc[j].x*ov[j].x + acc[j].y*ov[j].y + acc[j].z*ov[j].z + acc[j].w*ov[j].w;
      d += __shfl_xor(d, 1);
      d += __shfl_xor(d, 2);
      d += __shfl_xor(d, 4);
      d += __shfl_xor(d, 8);
      pd[j] = d;
    }
    if ((tid & 15) == 0) {
      #pragma unroll
      for (int j = 0; j < 4; ++j) {
        const size_t li = (size_t)(c*Bb + tb + j)*Rr + r;
        const float base = (pass == 1) ? lg[c*Rr + r] : gL1[li];
        dst[li] = base + pd[j];
      }
    }
    __syncthreads();
  }
}

__global__ void kf_softmax(int dir){  // dir 0: gL1->gLp ; 1: gLp->gL1
  __shared__ float sred[8];
  const size_t idx = blockIdx.x;
  const float* src = (dir == 0) ? gL1 : gLp;
  float*       dst = (dir == 0) ? gLp : gL1;
  softmax_row(src + idx*Rr, dst + idx*Rr, sred);
}

__global__ void kf_squash(float* __restrict__ out, int toFinal){  // grid C*B, block 64
  const size_t idx = blockIdx.x;
  const int t = threadIdx.x;
  const float s = gS[idx*Oo + t];
  float t2 = s*s;
  #pragma unroll
  for (int off = 1; off < 64; off <<= 1) t2 += __shfl_xor(t2, off);
  float* dst = toFinal ? out : gOut;
  dst[idx*Oo + t] = s * (t2 / ((1.0f + t2) * sqrtf(t2)));
}

// ---------------- launch ----------------
extern "C" void kernel_launch(void* const* d_in, const int* in_sizes, int n_in,
                              void* d_out, int out_size, void* d_ws, size_t ws_size,
                              hipStream_t stream) {
  const float* x  = (const float*)d_in[0];   // (B,R,I)
  const float* w  = (const float*)d_in[1];   // (C,R,I,O)
  const float* lg = (const float*)d_in[2];   // (C,1,R,1,1)
  float* out = (float*)d_out;                // (C,B,1,1,O)

  const dim3 gTiles(Cc, Rr/RT);
  const int  zb = (Cc*Bb*Oo + 255)/256;

  kz_zeroS<<<dim3(zb), 256, 0, stream>>>();
  k0f<<<dim3(Cc), 256, 0, stream>>>(lg);

  const size_t needP = (size_t)Cc*Bb*Rr*Oo*sizeof(float);
  if (ws_size >= needP) {
    float* P = (float*)d_ws;
    k1_priors<<<gTiles, 256, 0, stream>>>(x, w, P);
    k3_routing<<<dim3(Bb, Cc), 256, 0, stream>>>(P, lg, out);
  } else {
    kf_sum   <<<gTiles, 256, 0, stream>>>(x, w, 0);
    kf_squash<<<dim3(Cc*Bb), 64, 0, stream>>>(out, 0);
    kf_delta <<<gTiles, 256, 0, stream>>>(x, w, lg, 1);
    kf_softmax<<<dim3(Cc*Bb), 256, 0, stream>>>(0);
    kz_zeroS <<<dim3(zb), 256, 0, stream>>>();
    kf_sum   <<<gTiles, 256, 0, stream>>>(x, w, 1);
    kf_squash<<<dim3(Cc*Bb), 64, 0, stream>>>(out, 0);
    kf_delta <<<gTiles, 256, 0, stream>>>(x, w, lg, 2);
    kf_softmax<<<dim3(Cc*Bb), 256, 0, stream>>>(1);
    kz_zeroS <<<dim3(zb), 256, 0, stream>>>();
    kf_sum   <<<gTiles, 256, 0, stream>>>(x, w, 2);
    kf_squash<<<dim3(Cc*Bb), 64, 0, stream>>>(out, 1);
  }
}

// Round 3
// 632.293 us; speedup vs baseline: 1.0963x; 1.0963x over previous
//
#include <hip/hip_runtime.h>
#include <math.h>

#define Cc 16
#define Bb 64
#define Rr 1152
#define Ii 64
#define Oo 64
#define CH 4          // capsules per chunk
#define NRB 128       // r-blocks per c in k1
#define RT 9          // Rr / NRB
#define RTF 8         // fallback r-tile

static __device__ __forceinline__ float4 ld4(const float* p){ return *reinterpret_cast<const float4*>(p); }
static __device__ __forceinline__ void st4(float* p, float4 v){ *reinterpret_cast<float4*>(p) = v; }

static __device__ __forceinline__ void gl_lds16(const float4* g, float4* l){
  __builtin_amdgcn_global_load_lds(
      (const __attribute__((address_space(1))) void*)g,
      (__attribute__((address_space(3))) void*)l, 16, 0, 0);
}

// ---- small scratch for fallback path ----
__device__ float gProbs0[Cc*Rr];
__device__ float gS[Cc*Bb*Oo];
__device__ float gOut[Cc*Bb*Oo];
__device__ float gL1[(size_t)Cc*Bb*Rr];
__device__ float gLp[(size_t)Cc*Bb*Rr];

__global__ void kz_zeroS(){
  const int i = blockIdx.x*256 + threadIdx.x;
  if (i < Cc*Bb*Oo) gS[i] = 0.f;
}

// ---- softmax over a row of length Rr, block=256 ----
static __device__ void softmax_row(const float* __restrict__ L, float* __restrict__ out,
                                   float* __restrict__ sred){
  const int tid = threadIdx.x;
  float m = -3.4e38f;
  for (int r = tid; r < Rr; r += 256) m = fmaxf(m, L[r]);
  #pragma unroll
  for (int off = 1; off < 64; off <<= 1) m = fmaxf(m, __shfl_xor(m, off));
  if ((tid & 63) == 0) sred[tid >> 6] = m;
  __syncthreads();
  m = fmaxf(fmaxf(sred[0], sred[1]), fmaxf(sred[2], sred[3]));
  float s = 0.f;
  for (int r = tid; r < Rr; r += 256) s += __expf(L[r] - m);
  #pragma unroll
  for (int off = 1; off < 64; off <<= 1) s += __shfl_xor(s, off);
  if ((tid & 63) == 0) sred[4 + (tid >> 6)] = s;
  __syncthreads();
  s = sred[4] + sred[5] + sred[6] + sred[7];
  const float inv = 1.0f / s;
  for (int r = tid; r < Rr; r += 256) out[r] = __expf(L[r] - m) * inv;
}

__global__ void k0f(const float* __restrict__ lg){        // fallback: -> gProbs0
  __shared__ float sred[8];
  softmax_row(lg + blockIdx.x*Rr, gProbs0 + blockIdx.x*Rr, sred);
}
__global__ void k0p(const float* __restrict__ lg, float* __restrict__ pr){  // fast: -> ws
  __shared__ float sred[8];
  softmax_row(lg + blockIdx.x*Rr, pr + blockIdx.x*Rr, sred);
}

static __device__ __forceinline__ void fma_row(float4& a, const float4 xv,
    const float4 w0, const float4 w1, const float4 w2, const float4 w3){
  a.x = fmaf(xv.x, w0.x, fmaf(xv.y, w1.x, fmaf(xv.z, w2.x, fmaf(xv.w, w3.x, a.x))));
  a.y = fmaf(xv.x, w0.y, fmaf(xv.y, w1.y, fmaf(xv.z, w2.y, fmaf(xv.w, w3.y, a.y))));
  a.z = fmaf(xv.x, w0.z, fmaf(xv.y, w1.z, fmaf(xv.z, w2.z, fmaf(xv.w, w3.z, a.z))));
  a.w = fmaf(xv.x, w0.w, fmaf(xv.y, w1.w, fmaf(xv.z, w2.w, fmaf(xv.w, w3.w, a.w))));
}

// ============================ FAST PATH ============================
// async stage one (W[c,r], X[:,r,:]) pair into LDS buffers (linear dest; X source pre-swizzled)
static __device__ __forceinline__ void stage_async(const float4* __restrict__ xsrc,
    const float4* __restrict__ wsrc, int r, int wv, int ln,
    float4* __restrict__ Wb, float4* __restrict__ Xb){
  #pragma unroll
  for (int qq = 0; qq < 4; ++qq) {
    const int base = (wv*4 + qq) * 64;
    const int p    = base + ln;
    gl_lds16(wsrc + p, Wb + base);
    const int b  = p >> 4;
    const int lc = (p & 15) ^ ((b >> 2) & 3);     // X swizzle: spread bank quads across row groups
    gl_lds16(xsrc + (((size_t)(b*Rr + r)) << 4) + lc, Xb + base);
  }
}

__launch_bounds__(256)
__global__ void k1_priors(const float* __restrict__ x, const float* __restrict__ w,
                          const float* __restrict__ probs0, int c0,
                          float* __restrict__ P, float* __restrict__ Sp){
  const int ci  = blockIdx.x;
  const int c   = c0 + ci;
  const int rb  = blockIdx.y;
  const int r0  = rb * RT;
  const int tid = threadIdx.x;
  const int q   = tid & 15;
  const int to  = q * 4;
  const int tb  = (tid >> 4) * 4;
  const int wv  = tid >> 6;
  const int ln  = tid & 63;
  const int sx  = (tb >> 2) & 3;

  __shared__ float4 Wl[2][1024];   // 16 KB each
  __shared__ float4 Xl[2][1024];

  const float4* xsrc = reinterpret_cast<const float4*>(x);

  float4 s0a[4];
  #pragma unroll
  for (int j = 0; j < 4; ++j) s0a[j] = make_float4(0.f,0.f,0.f,0.f);

  int buf = 0;
  stage_async(xsrc, reinterpret_cast<const float4*>(w) + (size_t)(c*Rr + r0)*1024,
              r0, wv, ln, Wl[0], Xl[0]);
  __syncthreads();

  for (int rr = 0; rr < RT; ++rr) {
    const int r = r0 + rr;
    if (rr + 1 < RT)
      stage_async(xsrc, reinterpret_cast<const float4*>(w) + (size_t)(c*Rr + r + 1)*1024,
                  r + 1, wv, ln, Wl[buf^1], Xl[buf^1]);

    const float4* W4 = Wl[buf];
    const float4* X4 = Xl[buf];
    float4 acc0 = make_float4(0.f,0.f,0.f,0.f);
    float4 acc1 = acc0, acc2 = acc0, acc3 = acc0;

    #pragma unroll
    for (int kg = 0; kg < 16; ++kg) {
      const float4 wv0 = W4[(kg*4+0)*16 + q];
      const float4 wv1 = W4[(kg*4+1)*16 + q];
      const float4 wv2 = W4[(kg*4+2)*16 + q];
      const float4 wv3 = W4[(kg*4+3)*16 + q];
      const int xc = kg ^ sx;
      const float4 xv0 = X4[(tb+0)*16 + xc];
      const float4 xv1 = X4[(tb+1)*16 + xc];
      const float4 xv2 = X4[(tb+2)*16 + xc];
      const float4 xv3 = X4[(tb+3)*16 + xc];
      fma_row(acc0, xv0, wv0, wv1, wv2, wv3);
      fma_row(acc1, xv1, wv0, wv1, wv2, wv3);
      fma_row(acc2, xv2, wv0, wv1, wv2, wv3);
      fma_row(acc3, xv3, wv0, wv1, wv2, wv3);
    }

    const float pr = probs0[c*Rr + r];
    st4(&P[(((size_t)(ci*Bb + tb+0))*Rr + r)*Oo + to], acc0);
    st4(&P[(((size_t)(ci*Bb + tb+1))*Rr + r)*Oo + to], acc1);
    st4(&P[(((size_t)(ci*Bb + tb+2))*Rr + r)*Oo + to], acc2);
    st4(&P[(((size_t)(ci*Bb + tb+3))*Rr + r)*Oo + to], acc3);
    s0a[0].x = fmaf(pr, acc0.x, s0a[0].x); s0a[0].y = fmaf(pr, acc0.y, s0a[0].y);
    s0a[0].z = fmaf(pr, acc0.z, s0a[0].z); s0a[0].w = fmaf(pr, acc0.w, s0a[0].w);
    s0a[1].x = fmaf(pr, acc1.x, s0a[1].x); s0a[1].y = fmaf(pr, acc1.y, s0a[1].y);
    s0a[1].z = fmaf(pr, acc1.z, s0a[1].z); s0a[1].w = fmaf(pr, acc1.w, s0a[1].w);
    s0a[2].x = fmaf(pr, acc2.x, s0a[2].x); s0a[2].y = fmaf(pr, acc2.y, s0a[2].y);
    s0a[2].z = fmaf(pr, acc2.z, s0a[2].z); s0a[2].w = fmaf(pr, acc2.w, s0a[2].w);
    s0a[3].x = fmaf(pr, acc3.x, s0a[3].x); s0a[3].y = fmaf(pr, acc3.y, s0a[3].y);
    s0a[3].z = fmaf(pr, acc3.z, s0a[3].z); s0a[3].w = fmaf(pr, acc3.w, s0a[3].w);

    __syncthreads();
    buf ^= 1;
  }

  #pragma unroll
  for (int j = 0; j < 4; ++j)
    st4(&Sp[((((size_t)ci*NRB) + rb)*Bb + tb + j)*Oo + to], s0a[j]);
}

// reduce Sp over rb, squash -> out0[ci,b,:]
__launch_bounds__(256)
__global__ void k2_reduce(const float* __restrict__ Sp, float* __restrict__ out0){
  const int blk = blockIdx.x;              // ci*64 + b
  const int ci  = blk >> 6, b = blk & 63;
  const int wv  = threadIdx.x >> 6, o = threadIdx.x & 63;
  __shared__ float part[4][64];
  float s = 0.f;
  #pragma unroll 4
  for (int rb = wv*32; rb < wv*32 + 32; ++rb)
    s += Sp[((((size_t)ci*NRB) + rb)*Bb + b)*Oo + o];
  part[wv][o] = s;
  __syncthreads();
  if (threadIdx.x < 64) {
    s = part[0][o] + part[1][o] + part[2][o] + part[3][o];
    float t2 = s*s;
    #pragma unroll
    for (int off = 1; off < 64; off <<= 1) t2 += __shfl_xor(t2, off);
    out0[(size_t)blk*Oo + o] = s * (t2 / ((1.0f + t2) * sqrtf(t2)));
  }
}

__launch_bounds__(512)
__global__ void k3_routing(const float* __restrict__ P, const float* __restrict__ out0,
                           const float* __restrict__ lg0g, int c0,
                           float* __restrict__ out){
  const int b   = blockIdx.x;
  const int ci  = blockIdx.y;
  const int c   = c0 + ci;
  const int tid = threadIdx.x;
  const int wv  = tid >> 6;         // 0..7
  const int ln  = tid & 63;
  const int g   = ln >> 4;          // 0..3
  const int q   = ln & 15;
  const int o4  = q * 4;
  const int pid = wv*4 + g;         // 0..31

  __shared__ float lg0[Rr];
  __shared__ float lgs1[Rr];
  __shared__ float outv[Oo];
  __shared__ float marr[32], larr[32];
  __shared__ float sarr[32*Oo];

  for (int r = tid; r < Rr; r += 512) lg0[r] = lg0g[c*Rr + r];
  if (tid < 64) outv[tid] = out0[((size_t)(ci*Bb + b))*Oo + tid];
  __syncthreads();

  const float4* Pcb = reinterpret_cast<const float4*>(P) + ((size_t)(ci*Bb + b))*Rr*16;
  const int rbase = wv*4 + g;

  #pragma unroll 1
  for (int pass = 1; pass <= 2; ++pass) {
    float m = -3.4e38f, l = 0.f;
    float4 sa = make_float4(0.f,0.f,0.f,0.f);
    const float4 ov = ld4(&outv[o4]);

    #pragma unroll 1
    for (int it = 0; it < 9; ++it) {
      const int r0i = it*128 + rbase;
      const float4 pv0 = Pcb[(r0i +  0)*16 + q];
      const float4 pv1 = Pcb[(r0i + 32)*16 + q];
      const float4 pv2 = Pcb[(r0i + 64)*16 + q];
      const float4 pv3 = Pcb[(r0i + 96)*16 + q];

      float d0 = pv0.x*ov.x + pv0.y*ov.y + pv0.z*ov.z + pv0.w*ov.w;
      float d1 = pv1.x*ov.x + pv1.y*ov.y + pv1.z*ov.z + pv1.w*ov.w;
      float d2 = pv2.x*ov.x + pv2.y*ov.y + pv2.z*ov.z + pv2.w*ov.w;
      float d3 = pv3.x*ov.x + pv3.y*ov.y + pv3.z*ov.z + pv3.w*ov.w;
      #pragma unroll
      for (int off = 1; off < 16; off <<= 1) {
        d0 += __shfl_xor(d0, off);
        d1 += __shfl_xor(d1, off);
        d2 += __shfl_xor(d2, off);
        d3 += __shfl_xor(d3, off);
      }
      float b0, b1, b2, b3;
      if (pass == 1) { b0 = lg0[r0i]; b1 = lg0[r0i+32]; b2 = lg0[r0i+64]; b3 = lg0[r0i+96]; }
      else           { b0 = lgs1[r0i]; b1 = lgs1[r0i+32]; b2 = lgs1[r0i+64]; b3 = lgs1[r0i+96]; }
      const float l0 = b0 + d0, l1 = b1 + d1, l2 = b2 + d2, l3 = b3 + d3;
      if (pass == 1 && q == 0) {
        lgs1[r0i] = l0; lgs1[r0i+32] = l1; lgs1[r0i+64] = l2; lgs1[r0i+96] = l3;
      }
      const float mx = fmaxf(fmaxf(fmaxf(l0, l1), fmaxf(l2, l3)), m);
      const float wo = __expf(m - mx);
      const float e0 = __expf(l0 - mx), e1 = __expf(l1 - mx);
      const float e2 = __expf(l2 - mx), e3 = __expf(l3 - mx);
      l = l*wo + e0 + e1 + e2 + e3;
      sa.x = fmaf(pv0.x, e0, fmaf(pv1.x, e1, fmaf(pv2.x, e2, fmaf(pv3.x, e3, sa.x*wo))));
      sa.y = fmaf(pv0.y, e0, fmaf(pv1.y, e1, fmaf(pv2.y, e2, fmaf(pv3.y, e3, sa.y*wo))));
      sa.z = fmaf(pv0.z, e0, fmaf(pv1.z, e1, fmaf(pv2.z, e2, fmaf(pv3.z, e3, sa.z*wo))));
      sa.w = fmaf(pv0.w, e0, fmaf(pv1.w, e1, fmaf(pv2.w, e2, fmaf(pv3.w, e3, sa.w*wo))));
      m = mx;
    }

    if (q == 0) { marr[pid] = m; larr[pid] = l; }
    st4(&sarr[pid*Oo + o4], sa);
    __syncthreads();

    if (tid < 64) {
      float M = -3.4e38f;
      #pragma unroll
      for (int p = 0; p < 32; ++p) M = fmaxf(M, marr[p]);
      float L = 0.f, sv = 0.f;
      #pragma unroll
      for (int p = 0; p < 32; ++p) {
        const float f = __expf(marr[p] - M);
        L += larr[p] * f;
        sv = fmaf(sarr[p*Oo + tid], f, sv);
      }
      const float s = sv / L;
      float t2 = s*s;
      #pragma unroll
      for (int off = 1; off < 64; off <<= 1) t2 += __shfl_xor(t2, off);
      outv[tid] = s * (t2 / ((1.0f + t2) * sqrtf(t2)));
    }
    __syncthreads();
  }

  if (tid < 64) out[((size_t)c*Bb + b)*Oo + tid] = outv[tid];
}

// ============================ FALLBACK PATH ============================
static __device__ void stage_gemm(const float* __restrict__ x, const float* __restrict__ w,
                                  int c, int r, int tid, int tb, int to,
                                  float* __restrict__ Xs, float* __restrict__ Ws,
                                  float4* __restrict__ acc){
  const float4* wsrc = reinterpret_cast<const float4*>(w + (size_t)(c*Rr + r) * (Ii*Oo));
  #pragma unroll
  for (int qq = 0; qq < 4; ++qq) {
    const int fi = tid + 256*qq;
    reinterpret_cast<float4*>(Ws)[fi] = wsrc[fi];
    const int b  = fi >> 4;
    const int i4 = (fi & 15) << 2;
    st4(&Xs[b*68 + i4], ld4(x + (size_t)(b*Rr + r)*Ii + i4));
  }
  __syncthreads();
  #pragma unroll
  for (int j = 0; j < 4; ++j) acc[j] = make_float4(0.f,0.f,0.f,0.f);
  #pragma unroll
  for (int i4 = 0; i4 < Ii; i4 += 4) {
    const float4 xv0 = ld4(&Xs[(tb+0)*68 + i4]);
    const float4 xv1 = ld4(&Xs[(tb+1)*68 + i4]);
    const float4 xv2 = ld4(&Xs[(tb+2)*68 + i4]);
    const float4 xv3 = ld4(&Xs[(tb+3)*68 + i4]);
    const float4 wv0 = ld4(&Ws[(i4+0)*64 + to]);
    const float4 wv1 = ld4(&Ws[(i4+1)*64 + to]);
    const float4 wv2 = ld4(&Ws[(i4+2)*64 + to]);
    const float4 wv3 = ld4(&Ws[(i4+3)*64 + to]);
    fma_row(acc[0], xv0, wv0, wv1, wv2, wv3);
    fma_row(acc[1], xv1, wv0, wv1, wv2, wv3);
    fma_row(acc[2], xv2, wv0, wv1, wv2, wv3);
    fma_row(acc[3], xv3, wv0, wv1, wv2, wv3);
  }
}

__launch_bounds__(256)
__global__ void kf_sum(const float* __restrict__ x, const float* __restrict__ w, int which){
  const int c = blockIdx.x, r0 = blockIdx.y * RTF, tid = threadIdx.x;
  const int to = (tid & 15) * 4, tb = (tid >> 4) * 4;
  __shared__ float Xs[64*68];
  __shared__ float Ws[64*64];
  const float* pcbr = (which == 1) ? gLp : gL1;
  float4 sa[4];
  #pragma unroll
  for (int j = 0; j < 4; ++j) sa[j] = make_float4(0.f,0.f,0.f,0.f);
  for (int rr = 0; rr < RTF; ++rr) {
    const int r = r0 + rr;
    float4 acc[4];
    stage_gemm(x, w, c, r, tid, tb, to, Xs, Ws, acc);
    #pragma unroll
    for (int j = 0; j < 4; ++j) {
      const float wt = (which == 0) ? gProbs0[c*Rr + r]
                                    : pcbr[(size_t)(c*Bb + tb + j)*Rr + r];
      sa[j].x = fmaf(wt, acc[j].x, sa[j].x);
      sa[j].y = fmaf(wt, acc[j].y, sa[j].y);
      sa[j].z = fmaf(wt, acc[j].z, sa[j].z);
      sa[j].w = fmaf(wt, acc[j].w, sa[j].w);
    }
    __syncthreads();
  }
  #pragma unroll
  for (int j = 0; j < 4; ++j) {
    float* dst = &gS[(size_t)(c*Bb + tb + j)*Oo + to];
    atomicAdd(dst + 0, sa[j].x);
    atomicAdd(dst + 1, sa[j].y);
    atomicAdd(dst + 2, sa[j].z);
    atomicAdd(dst + 3, sa[j].w);
  }
}

__launch_bounds__(256)
__global__ void kf_delta(const float* __restrict__ x, const float* __restrict__ w,
                         const float* __restrict__ lg, int pass){
  const int c = blockIdx.x, r0 = blockIdx.y * RTF, tid = threadIdx.x;
  const int to = (tid & 15) * 4, tb = (tid >> 4) * 4;
  __shared__ float Xs[64*68];
  __shared__ float Ws[64*64];
  float* dst = (pass == 1) ? gL1 : gLp;
  float4 ov[4];
  #pragma unroll
  for (int j = 0; j < 4; ++j) ov[j] = ld4(&gOut[(size_t)(c*Bb + tb + j)*Oo + to]);
  for (int rr = 0; rr < RTF; ++rr) {
    const int r = r0 + rr;
    float4 acc[4];
    stage_gemm(x, w, c, r, tid, tb, to, Xs, Ws, acc);
    float pd[4];
    #pragma unroll
    for (int j = 0; j < 4; ++j) {
      float d = acc[j].x*ov[j].x + acc[j].y*ov[j].y + acc[j].z*ov[j].z + acc[j].w*ov[j].w;
      d += __shfl_xor(d, 1); d += __shfl_xor(d, 2);
      d += __shfl_xor(d, 4); d += __shfl_xor(d, 8);
      pd[j] = d;
    }
    if ((tid & 15) == 0) {
      #pragma unroll
      for (int j = 0; j < 4; ++j) {
        const size_t li = (size_t)(c*Bb + tb + j)*Rr + r;
        const float base = (pass == 1) ? lg[c*Rr + r] : gL1[li];
        dst[li] = base + pd[j];
      }
    }
    __syncthreads();
  }
}

__global__ void kf_softmax(int dir){
  __shared__ float sred[8];
  const size_t idx = blockIdx.x;
  const float* src = (dir == 0) ? gL1 : gLp;
  float*       dst = (dir == 0) ? gLp : gL1;
  softmax_row(src + idx*Rr, dst + idx*Rr, sred);
}

__global__ void kf_squash(float* __restrict__ out, int toFinal){
  const size_t idx = blockIdx.x;
  const int t = threadIdx.x;
  const float s = gS[idx*Oo + t];
  float t2 = s*s;
  #pragma unroll
  for (int off = 1; off < 64; off <<= 1) t2 += __shfl_xor(t2, off);
  float* dst = toFinal ? out : gOut;
  dst[idx*Oo + t] = s * (t2 / ((1.0f + t2) * sqrtf(t2)));
}

// ============================ launch ============================
extern "C" void kernel_launch(void* const* d_in, const int* in_sizes, int n_in,
                              void* d_out, int out_size, void* d_ws, size_t ws_size,
                              hipStream_t stream) {
  const float* x  = (const float*)d_in[0];
  const float* w  = (const float*)d_in[1];
  const float* lg = (const float*)d_in[2];
  float* out = (float*)d_out;
  float* ws  = (float*)d_ws;

  const size_t nP  = (size_t)CH*Bb*Rr*Oo;    // 18.9M floats
  const size_t nSp = (size_t)CH*NRB*Bb*Oo;   // 2.1M
  const size_t nO0 = (size_t)CH*Bb*Oo;
  const size_t nPr = (size_t)Cc*Rr;
  const size_t need = (nP + nSp + nO0 + nPr) * sizeof(float);

  if (ws_size >= need) {
    float* P   = ws;
    float* Sp  = P + nP;
    float* o0  = Sp + nSp;
    float* pr  = o0 + nO0;
    k0p<<<dim3(Cc), 256, 0, stream>>>(lg, pr);
    for (int c0 = 0; c0 < Cc; c0 += CH) {
      k1_priors<<<dim3(CH, NRB), 256, 0, stream>>>(x, w, pr, c0, P, Sp);
      k2_reduce<<<dim3(CH*Bb), 256, 0, stream>>>(Sp, o0);
      k3_routing<<<dim3(Bb, CH), 512, 0, stream>>>(P, o0, lg, c0, out);
    }
  } else {
    const dim3 gTiles(Cc, Rr/RTF);
    const int  zb = (Cc*Bb*Oo + 255)/256;
    kz_zeroS<<<dim3(zb), 256, 0, stream>>>();
    k0f<<<dim3(Cc), 256, 0, stream>>>(lg);
    kf_sum   <<<gTiles, 256, 0, stream>>>(x, w, 0);
    kf_squash<<<dim3(Cc*Bb), 64, 0, stream>>>(out, 0);
    kf_delta <<<gTiles, 256, 0, stream>>>(x, w, lg, 1);
    kf_softmax<<<dim3(Cc*Bb), 256, 0, stream>>>(0);
    kz_zeroS <<<dim3(zb), 256, 0, stream>>>();
    kf_sum   <<<gTiles, 256, 0, stream>>>(x, w, 1);
    kf_squash<<<dim3(Cc*Bb), 64, 0, stream>>>(out, 0);
    kf_delta <<<gTiles, 256, 0, stream>>>(x, w, lg, 2);
    kf_softmax<<<dim3(Cc*Bb), 256, 0, stream>>>(1);
    kz_zeroS <<<dim3(zb), 256, 0, stream>>>();
    kf_sum   <<<gTiles, 256, 0, stream>>>(x, w, 2);
    kf_squash<<<dim3(Cc*Bb), 64, 0, stream>>>(out, 1);
  }
}

// Round 4
// 585.415 us; speedup vs baseline: 1.1840x; 1.0801x over previous
//
#include <hip/hip_runtime.h>
#include <math.h>

#define Cc 16
#define Bb 64
#define Rr 1152
#define Ii 64
#define Oo 64
#define CH 8          // capsules per chunk (2 chunks)
#define RT 4          // r's per k1 block
#define NRB 288       // Rr / RT
#define RTF 8         // fallback r-tile

typedef float f4v __attribute__((ext_vector_type(4)));

static __device__ __forceinline__ float4 ld4(const float* p){ return *reinterpret_cast<const float4*>(p); }
static __device__ __forceinline__ void st4(float* p, float4 v){ *reinterpret_cast<float4*>(p) = v; }
static __device__ __forceinline__ float4 ntld4(const float4* p){
  f4v v = __builtin_nontemporal_load(reinterpret_cast<const f4v*>(p));
  float4 r; r.x = v.x; r.y = v.y; r.z = v.z; r.w = v.w; return r;
}

// ---- small scratch for fallback path ----
__device__ float gProbs0[Cc*Rr];
__device__ float gS[Cc*Bb*Oo];
__device__ float gOut[Cc*Bb*Oo];
__device__ float gL1[(size_t)Cc*Bb*Rr];
__device__ float gLp[(size_t)Cc*Bb*Rr];

__global__ void kz_zeroS(){
  const int i = blockIdx.x*256 + threadIdx.x;
  if (i < Cc*Bb*Oo) gS[i] = 0.f;
}

// ---- softmax over a row of length Rr, block=256 ----
static __device__ void softmax_row(const float* __restrict__ L, float* __restrict__ out,
                                   float* __restrict__ sred){
  const int tid = threadIdx.x;
  float m = -3.4e38f;
  for (int r = tid; r < Rr; r += 256) m = fmaxf(m, L[r]);
  #pragma unroll
  for (int off = 1; off < 64; off <<= 1) m = fmaxf(m, __shfl_xor(m, off));
  if ((tid & 63) == 0) sred[tid >> 6] = m;
  __syncthreads();
  m = fmaxf(fmaxf(sred[0], sred[1]), fmaxf(sred[2], sred[3]));
  float s = 0.f;
  for (int r = tid; r < Rr; r += 256) s += __expf(L[r] - m);
  #pragma unroll
  for (int off = 1; off < 64; off <<= 1) s += __shfl_xor(s, off);
  if ((tid & 63) == 0) sred[4 + (tid >> 6)] = s;
  __syncthreads();
  s = sred[4] + sred[5] + sred[6] + sred[7];
  const float inv = 1.0f / s;
  for (int r = tid; r < Rr; r += 256) out[r] = __expf(L[r] - m) * inv;
}

__global__ void k0f(const float* __restrict__ lg){
  __shared__ float sred[8];
  softmax_row(lg + blockIdx.x*Rr, gProbs0 + blockIdx.x*Rr, sred);
}
__global__ void k0p(const float* __restrict__ lg, float* __restrict__ pr){
  __shared__ float sred[8];
  softmax_row(lg + blockIdx.x*Rr, pr + blockIdx.x*Rr, sred);
}

static __device__ __forceinline__ void fma_row(float4& a, const float4 xv,
    const float4 w0, const float4 w1, const float4 w2, const float4 w3){
  a.x = fmaf(xv.x, w0.x, fmaf(xv.y, w1.x, fmaf(xv.z, w2.x, fmaf(xv.w, w3.x, a.x))));
  a.y = fmaf(xv.x, w0.y, fmaf(xv.y, w1.y, fmaf(xv.z, w2.y, fmaf(xv.w, w3.y, a.y))));
  a.z = fmaf(xv.x, w0.z, fmaf(xv.y, w1.z, fmaf(xv.z, w2.z, fmaf(xv.w, w3.z, a.z))));
  a.w = fmaf(xv.x, w0.w, fmaf(xv.y, w1.w, fmaf(xv.z, w2.w, fmaf(xv.w, w3.w, a.w))));
}

// ============================ FAST PATH ============================
// T14 reg-staged prefetch. LDS single-buffered (33 KB -> 4 blocks/CU).
// X LDS layout XOR-swizzled: row b, col c stored at Xl[b*16 + (c ^ (b>>2))].
struct Stage { float4 wv[4]; float4 xv[4]; };

static __device__ __forceinline__ void issue_loads(const float4* __restrict__ wsrcR,
    const float4* __restrict__ xsrc, int r, int tid, Stage& st){
  #pragma unroll
  for (int qq = 0; qq < 4; ++qq) {
    const int p = tid + 256*qq;
    st.wv[qq] = ntld4(wsrcR + p);                       // W: stream, don't cache (protect L3 for P)
    const int b = p >> 4, col = p & 15;
    st.xv[qq] = ld4((const float*)(xsrc + ((size_t)(b*Rr + r) << 4) + col));
  }
}

static __device__ __forceinline__ void write_lds(float4* __restrict__ Wl, float4* __restrict__ Xl,
                                                 int tid, const Stage& st){
  #pragma unroll
  for (int qq = 0; qq < 4; ++qq) {
    const int p = tid + 256*qq;
    Wl[p] = st.wv[qq];
    const int b = p >> 4, col = p & 15;
    Xl[b*16 + (col ^ (b >> 2))] = st.xv[qq];
  }
}

__launch_bounds__(256)
__global__ void k1_priors(const float* __restrict__ x, const float* __restrict__ w,
                          const float* __restrict__ probs0, int c0,
                          float* __restrict__ P, float* __restrict__ Sp){
  const int ci  = blockIdx.x;
  const int c   = c0 + ci;
  const int rb  = blockIdx.y;
  const int r0  = rb * RT;
  const int tid = threadIdx.x;
  const int q   = tid & 15;
  const int to  = q * 4;
  const int g   = tid >> 4;          // 0..15
  const int tb  = g * 4;

  __shared__ float4 Wl[1024];        // 16 KB, linear
  __shared__ float4 Xl[1024];        // 16 KB, swizzled

  const float4* xsrc = reinterpret_cast<const float4*>(x);
  const float4* wbase = reinterpret_cast<const float4*>(w) + (size_t)c*Rr*1024;

  float4 s0a[4];
  #pragma unroll
  for (int j = 0; j < 4; ++j) s0a[j] = make_float4(0.f,0.f,0.f,0.f);

  Stage st;
  issue_loads(wbase + (size_t)r0*1024, xsrc, r0, tid, st);
  write_lds(Wl, Xl, tid, st);
  __syncthreads();

  for (int rr = 0; rr < RT; ++rr) {
    const int r = r0 + rr;
    const bool more = (rr + 1 < RT);
    if (more) issue_loads(wbase + (size_t)(r+1)*1024, xsrc, r+1, tid, st);

    float4 acc0 = make_float4(0.f,0.f,0.f,0.f);
    float4 acc1 = acc0, acc2 = acc0, acc3 = acc0;
    #pragma unroll
    for (int kg = 0; kg < 16; ++kg) {
      const float4 wv0 = Wl[(kg*4+0)*16 + q];
      const float4 wv1 = Wl[(kg*4+1)*16 + q];
      const float4 wv2 = Wl[(kg*4+2)*16 + q];
      const float4 wv3 = Wl[(kg*4+3)*16 + q];
      const int xc = kg ^ g;                   // matches write swizzle: rows tb..tb+3 share (row>>2)==g
      const float4 xv0 = Xl[(tb+0)*16 + xc];
      const float4 xv1 = Xl[(tb+1)*16 + xc];
      const float4 xv2 = Xl[(tb+2)*16 + xc];
      const float4 xv3 = Xl[(tb+3)*16 + xc];
      fma_row(acc0, xv0, wv0, wv1, wv2, wv3);
      fma_row(acc1, xv1, wv0, wv1, wv2, wv3);
      fma_row(acc2, xv2, wv0, wv1, wv2, wv3);
      fma_row(acc3, xv3, wv0, wv1, wv2, wv3);
    }

    const float pr = probs0[c*Rr + r];
    st4(&P[(((size_t)(ci*Bb + tb+0))*Rr + r)*Oo + to], acc0);
    st4(&P[(((size_t)(ci*Bb + tb+1))*Rr + r)*Oo + to], acc1);
    st4(&P[(((size_t)(ci*Bb + tb+2))*Rr + r)*Oo + to], acc2);
    st4(&P[(((size_t)(ci*Bb + tb+3))*Rr + r)*Oo + to], acc3);
    s0a[0].x = fmaf(pr, acc0.x, s0a[0].x); s0a[0].y = fmaf(pr, acc0.y, s0a[0].y);
    s0a[0].z = fmaf(pr, acc0.z, s0a[0].z); s0a[0].w = fmaf(pr, acc0.w, s0a[0].w);
    s0a[1].x = fmaf(pr, acc1.x, s0a[1].x); s0a[1].y = fmaf(pr, acc1.y, s0a[1].y);
    s0a[1].z = fmaf(pr, acc1.z, s0a[1].z); s0a[1].w = fmaf(pr, acc1.w, s0a[1].w);
    s0a[2].x = fmaf(pr, acc2.x, s0a[2].x); s0a[2].y = fmaf(pr, acc2.y, s0a[2].y);
    s0a[2].z = fmaf(pr, acc2.z, s0a[2].z); s0a[2].w = fmaf(pr, acc2.w, s0a[2].w);
    s0a[3].x = fmaf(pr, acc3.x, s0a[3].x); s0a[3].y = fmaf(pr, acc3.y, s0a[3].y);
    s0a[3].z = fmaf(pr, acc3.z, s0a[3].z); s0a[3].w = fmaf(pr, acc3.w, s0a[3].w);

    if (more) {
      __syncthreads();               // all waves done reading LDS
      write_lds(Wl, Xl, tid, st);    // (compiler inserts vmcnt wait)
      __syncthreads();               // writes visible before next compute
    }
  }

  #pragma unroll
  for (int j = 0; j < 4; ++j)
    st4(&Sp[((((size_t)ci*NRB) + rb)*Bb + tb + j)*Oo + to], s0a[j]);
}

// reduce Sp over rb (NRB partials), squash -> out0[ci,b,:]
__launch_bounds__(256)
__global__ void k2_reduce(const float* __restrict__ Sp, float* __restrict__ out0){
  const int blk = blockIdx.x;              // ci*64 + b
  const int ci  = blk >> 6, b = blk & 63;
  const int wv  = threadIdx.x >> 6, o = threadIdx.x & 63;
  __shared__ float part[4][64];
  float s = 0.f;
  for (int rb = wv*(NRB/4); rb < (wv+1)*(NRB/4); ++rb)
    s += Sp[((((size_t)ci*NRB) + rb)*Bb + b)*Oo + o];
  part[wv][o] = s;
  __syncthreads();
  if (threadIdx.x < 64) {
    s = part[0][o] + part[1][o] + part[2][o] + part[3][o];
    float t2 = s*s;
    #pragma unroll
    for (int off = 1; off < 64; off <<= 1) t2 += __shfl_xor(t2, off);
    out0[(size_t)blk*Oo + o] = s * (t2 / ((1.0f + t2) * sqrtf(t2)));
  }
}

// routing: 1024 threads, 64 lane-groups of 16; group G handles r = G + 64j, j=0..17 (3-row batches)
__launch_bounds__(1024)
__global__ void k3_routing(const float* __restrict__ P, const float* __restrict__ out0,
                           const float* __restrict__ lg0g, int c0,
                           float* __restrict__ out){
  const int b   = blockIdx.x;
  const int ci  = blockIdx.y;
  const int c   = c0 + ci;
  const int tid = threadIdx.x;
  const int wv  = tid >> 6;         // 0..15
  const int ln  = tid & 63;
  const int gw  = ln >> 4;          // 0..3
  const int q   = ln & 15;
  const int o4  = q * 4;
  const int G   = wv*4 + gw;        // 0..63

  __shared__ float lg0[Rr];
  __shared__ float lgs1[Rr];
  __shared__ float outv[Oo];
  __shared__ float marr[64], larr[64];
  __shared__ float sarr[64*Oo];

  for (int r = tid; r < Rr; r += 1024) lg0[r] = lg0g[c*Rr + r];
  if (tid < 64) outv[tid] = out0[((size_t)(ci*Bb + b))*Oo + tid];
  __syncthreads();

  const float4* Pcb = reinterpret_cast<const float4*>(P) + ((size_t)(ci*Bb + b))*Rr*16;

  #pragma unroll 1
  for (int pass = 1; pass <= 2; ++pass) {
    float m = -3.4e38f, l = 0.f;
    float4 sa = make_float4(0.f,0.f,0.f,0.f);
    const float4 ov = ld4(&outv[o4]);

    #pragma unroll 1
    for (int j6 = 0; j6 < 6; ++j6) {
      const int r0i = G + 192*j6;                 // rows r0i, r0i+64, r0i+128
      const float4 pv0 = Pcb[(r0i +   0)*16 + q];
      const float4 pv1 = Pcb[(r0i +  64)*16 + q];
      const float4 pv2 = Pcb[(r0i + 128)*16 + q];

      float d0 = pv0.x*ov.x + pv0.y*ov.y + pv0.z*ov.z + pv0.w*ov.w;
      float d1 = pv1.x*ov.x + pv1.y*ov.y + pv1.z*ov.z + pv1.w*ov.w;
      float d2 = pv2.x*ov.x + pv2.y*ov.y + pv2.z*ov.z + pv2.w*ov.w;
      #pragma unroll
      for (int off = 1; off < 16; off <<= 1) {
        d0 += __shfl_xor(d0, off);
        d1 += __shfl_xor(d1, off);
        d2 += __shfl_xor(d2, off);
      }
      float b0, b1, b2;
      if (pass == 1) { b0 = lg0[r0i]; b1 = lg0[r0i+64]; b2 = lg0[r0i+128]; }
      else           { b0 = lgs1[r0i]; b1 = lgs1[r0i+64]; b2 = lgs1[r0i+128]; }
      const float l0 = b0 + d0, l1 = b1 + d1, l2 = b2 + d2;
      if (pass == 1 && q == 0) { lgs1[r0i] = l0; lgs1[r0i+64] = l1; lgs1[r0i+128] = l2; }
      const float mx = fmaxf(m, fmaxf(fmaxf(l0, l1), l2));
      const float wo = __expf(m - mx);
      const float e0 = __expf(l0 - mx), e1 = __expf(l1 - mx), e2 = __expf(l2 - mx);
      l = l*wo + e0 + e1 + e2;
      sa.x = fmaf(pv0.x, e0, fmaf(pv1.x, e1, fmaf(pv2.x, e2, sa.x*wo)));
      sa.y = fmaf(pv0.y, e0, fmaf(pv1.y, e1, fmaf(pv2.y, e2, sa.y*wo)));
      sa.z = fmaf(pv0.z, e0, fmaf(pv1.z, e1, fmaf(pv2.z, e2, sa.z*wo)));
      sa.w = fmaf(pv0.w, e0, fmaf(pv1.w, e1, fmaf(pv2.w, e2, sa.w*wo)));
      m = mx;
    }

    if (q == 0) { marr[G] = m; larr[G] = l; }
    st4(&sarr[G*Oo + o4], sa);
    __syncthreads();

    if (tid < 64) {
      float M = -3.4e38f;
      #pragma unroll
      for (int p = 0; p < 64; ++p) M = fmaxf(M, marr[p]);
      float L = 0.f, sv = 0.f;
      #pragma unroll 8
      for (int p = 0; p < 64; ++p) {
        const float f = __expf(marr[p] - M);
        L += larr[p] * f;
        sv = fmaf(sarr[p*Oo + tid], f, sv);
      }
      const float s = sv / L;
      float t2 = s*s;
      #pragma unroll
      for (int off = 1; off < 64; off <<= 1) t2 += __shfl_xor(t2, off);
      outv[tid] = s * (t2 / ((1.0f + t2) * sqrtf(t2)));
    }
    __syncthreads();
  }

  if (tid < 64) out[((size_t)c*Bb + b)*Oo + tid] = outv[tid];
}

// ============================ FALLBACK PATH (unchanged; never runs when ws is big) ============================
static __device__ void stage_gemm(const float* __restrict__ x, const float* __restrict__ w,
                                  int c, int r, int tid, int tb, int to,
                                  float* __restrict__ Xs, float* __restrict__ Ws,
                                  float4* __restrict__ acc){
  const float4* wsrc = reinterpret_cast<const float4*>(w + (size_t)(c*Rr + r) * (Ii*Oo));
  #pragma unroll
  for (int qq = 0; qq < 4; ++qq) {
    const int fi = tid + 256*qq;
    reinterpret_cast<float4*>(Ws)[fi] = wsrc[fi];
    const int b  = fi >> 4;
    const int i4 = (fi & 15) << 2;
    st4(&Xs[b*68 + i4], ld4(x + (size_t)(b*Rr + r)*Ii + i4));
  }
  __syncthreads();
  #pragma unroll
  for (int j = 0; j < 4; ++j) acc[j] = make_float4(0.f,0.f,0.f,0.f);
  #pragma unroll
  for (int i4 = 0; i4 < Ii; i4 += 4) {
    const float4 xv0 = ld4(&Xs[(tb+0)*68 + i4]);
    const float4 xv1 = ld4(&Xs[(tb+1)*68 + i4]);
    const float4 xv2 = ld4(&Xs[(tb+2)*68 + i4]);
    const float4 xv3 = ld4(&Xs[(tb+3)*68 + i4]);
    const float4 wv0 = ld4(&Ws[(i4+0)*64 + to]);
    const float4 wv1 = ld4(&Ws[(i4+1)*64 + to]);
    const float4 wv2 = ld4(&Ws[(i4+2)*64 + to]);
    const float4 wv3 = ld4(&Ws[(i4+3)*64 + to]);
    fma_row(acc[0], xv0, wv0, wv1, wv2, wv3);
    fma_row(acc[1], xv1, wv0, wv1, wv2, wv3);
    fma_row(acc[2], xv2, wv0, wv1, wv2, wv3);
    fma_row(acc[3], xv3, wv0, wv1, wv2, wv3);
  }
}

__launch_bounds__(256)
__global__ void kf_sum(const float* __restrict__ x, const float* __restrict__ w, int which){
  const int c = blockIdx.x, r0 = blockIdx.y * RTF, tid = threadIdx.x;
  const int to = (tid & 15) * 4, tb = (tid >> 4) * 4;
  __shared__ float Xs[64*68];
  __shared__ float Ws[64*64];
  const float* pcbr = (which == 1) ? gLp : gL1;
  float4 sa[4];
  #pragma unroll
  for (int j = 0; j < 4; ++j) sa[j] = make_float4(0.f,0.f,0.f,0.f);
  for (int rr = 0; rr < RTF; ++rr) {
    const int r = r0 + rr;
    float4 acc[4];
    stage_gemm(x, w, c, r, tid, tb, to, Xs, Ws, acc);
    #pragma unroll
    for (int j = 0; j < 4; ++j) {
      const float wt = (which == 0) ? gProbs0[c*Rr + r]
                                    : pcbr[(size_t)(c*Bb + tb + j)*Rr + r];
      sa[j].x = fmaf(wt, acc[j].x, sa[j].x);
      sa[j].y = fmaf(wt, acc[j].y, sa[j].y);
      sa[j].z = fmaf(wt, acc[j].z, sa[j].z);
      sa[j].w = fmaf(wt, acc[j].w, sa[j].w);
    }
    __syncthreads();
  }
  #pragma unroll
  for (int j = 0; j < 4; ++j) {
    float* dst = &gS[(size_t)(c*Bb + tb + j)*Oo + to];
    atomicAdd(dst + 0, sa[j].x);
    atomicAdd(dst + 1, sa[j].y);
    atomicAdd(dst + 2, sa[j].z);
    atomicAdd(dst + 3, sa[j].w);
  }
}

__launch_bounds__(256)
__global__ void kf_delta(const float* __restrict__ x, const float* __restrict__ w,
                         const float* __restrict__ lg, int pass){
  const int c = blockIdx.x, r0 = blockIdx.y * RTF, tid = threadIdx.x;
  const int to = (tid & 15) * 4, tb = (tid >> 4) * 4;
  __shared__ float Xs[64*68];
  __shared__ float Ws[64*64];
  float* dst = (pass == 1) ? gL1 : gLp;
  float4 ov[4];
  #pragma unroll
  for (int j = 0; j < 4; ++j) ov[j] = ld4(&gOut[(size_t)(c*Bb + tb + j)*Oo + to]);
  for (int rr = 0; rr < RTF; ++rr) {
    const int r = r0 + rr;
    float4 acc[4];
    stage_gemm(x, w, c, r, tid, tb, to, Xs, Ws, acc);
    float pd[4];
    #pragma unroll
    for (int j = 0; j < 4; ++j) {
      float d = acc[j].x*ov[j].x + acc[j].y*ov[j].y + acc[j].z*ov[j].z + acc[j].w*ov[j].w;
      d += __shfl_xor(d, 1); d += __shfl_xor(d, 2);
      d += __shfl_xor(d, 4); d += __shfl_xor(d, 8);
      pd[j] = d;
    }
    if ((tid & 15) == 0) {
      #pragma unroll
      for (int j = 0; j < 4; ++j) {
        const size_t li = (size_t)(c*Bb + tb + j)*Rr + r;
        const float base = (pass == 1) ? lg[c*Rr + r] : gL1[li];
        dst[li] = base + pd[j];
      }
    }
    __syncthreads();
  }
}

__global__ void kf_softmax(int dir){
  __shared__ float sred[8];
  const size_t idx = blockIdx.x;
  const float* src = (dir == 0) ? gL1 : gLp;
  float*       dst = (dir == 0) ? gLp : gL1;
  softmax_row(src + idx*Rr, dst + idx*Rr, sred);
}

__global__ void kf_squash(float* __restrict__ out, int toFinal){
  const size_t idx = blockIdx.x;
  const int t = threadIdx.x;
  const float s = gS[idx*Oo + t];
  float t2 = s*s;
  #pragma unroll
  for (int off = 1; off < 64; off <<= 1) t2 += __shfl_xor(t2, off);
  float* dst = toFinal ? out : gOut;
  dst[idx*Oo + t] = s * (t2 / ((1.0f + t2) * sqrtf(t2)));
}

// ============================ launch ============================
extern "C" void kernel_launch(void* const* d_in, const int* in_sizes, int n_in,
                              void* d_out, int out_size, void* d_ws, size_t ws_size,
                              hipStream_t stream) {
  const float* x  = (const float*)d_in[0];
  const float* w  = (const float*)d_in[1];
  const float* lg = (const float*)d_in[2];
  float* out = (float*)d_out;
  float* ws  = (float*)d_ws;

  const size_t nP  = (size_t)CH*Bb*Rr*Oo;      // 37.7M floats (151 MB)
  const size_t nSp = (size_t)CH*NRB*Bb*Oo;     // 9.4M (37.7 MB)
  const size_t nO0 = (size_t)CH*Bb*Oo;
  const size_t nPr = (size_t)Cc*Rr;
  const size_t need = (nP + nSp + nO0 + nPr) * sizeof(float);

  if (ws_size >= need) {
    float* P   = ws;
    float* Sp  = P + nP;
    float* o0  = Sp + nSp;
    float* pr  = o0 + nO0;
    k0p<<<dim3(Cc), 256, 0, stream>>>(lg, pr);
    for (int c0 = 0; c0 < Cc; c0 += CH) {
      k1_priors<<<dim3(CH, NRB), 256, 0, stream>>>(x, w, pr, c0, P, Sp);
      k2_reduce<<<dim3(CH*Bb), 256, 0, stream>>>(Sp, o0);
      k3_routing<<<dim3(Bb, CH), 1024, 0, stream>>>(P, o0, lg, c0, out);
    }
  } else {
    const dim3 gTiles(Cc, Rr/RTF);
    const int  zb = (Cc*Bb*Oo + 255)/256;
    kz_zeroS<<<dim3(zb), 256, 0, stream>>>();
    k0f<<<dim3(Cc), 256, 0, stream>>>(lg);
    kf_sum   <<<gTiles, 256, 0, stream>>>(x, w, 0);
    kf_squash<<<dim3(Cc*Bb), 64, 0, stream>>>(out, 0);
    kf_delta <<<gTiles, 256, 0, stream>>>(x, w, lg, 1);
    kf_softmax<<<dim3(Cc*Bb), 256, 0, stream>>>(0);
    kz_zeroS <<<dim3(zb), 256, 0, stream>>>();
    kf_sum   <<<gTiles, 256, 0, stream>>>(x, w, 1);
    kf_squash<<<dim3(Cc*Bb), 64, 0, stream>>>(out, 0);
    kf_delta <<<gTiles, 256, 0, stream>>>(x, w, lg, 2);
    kf_softmax<<<dim3(Cc*Bb), 256, 0, stream>>>(1);
    kz_zeroS <<<dim3(zb), 256, 0, stream>>>();
    kf_sum   <<<gTiles, 256, 0, stream>>>(x, w, 2);
    kf_squash<<<dim3(Cc*Bb), 64, 0, stream>>>(out, 1);
  }
}